// Round 7
// baseline (608.456 us; speedup 1.0000x reference)
//
#include <hip/hip_runtime.h>
#include <stdint.h>

#define HH 224
#define WW 224
#define NSEAM 7
#define BWIDTH 5
#define NP 11
#define BB 256
#define KK 64
#define YCH 4
#define YROWS (HH / YCH)
#define REP_DP 16
#define REP_LB 10

// DPP helpers (ctrl must be literal): row_shr:1=0x111 (dst[i]=src[i-1]),
// row_shl:1=0x101 (dst[i]=src[i+1]), row_ror:N=0x120+N. Rows = 16 lanes.
#define DPPF_OLD(old, src, ctrl) \
    __int_as_float(__builtin_amdgcn_update_dpp(__float_as_int(old), __float_as_int(src), ctrl, 0xF, 0xF, false))
#define DPPF_Z(src, ctrl) \
    __int_as_float(__builtin_amdgcn_update_dpp(0, __float_as_int(src), ctrl, 0xF, 0xF, true))
#define DPPI_Z(src, ctrl) \
    __builtin_amdgcn_update_dpp(0, (int)(src), ctrl, 0xF, 0xF, true)

// ---------------------------------------------------------------------------
// INSTRUMENTATION ROUND: dp repeated x16 and label walk repeated x10 inside
// their kernels so their dispatch durations exceed the harness fills (~88us)
// and appear in rocprof top-5, giving the true per-kernel split.
// Outputs remain bit-identical: dp iterations are idempotent; label's gacc
// accumulates exactly 10x every field (centroid = (10*sy)/(10*cnt) rounds
// identically), with fields widened to cnt:20 / sy:22 / sx:22 bits.
// ---------------------------------------------------------------------------
__global__ __launch_bounds__(256) void dp_kernel(const float* __restrict__ g,
                                                 int* __restrict__ paths,
                                                 unsigned long long* __restrict__ gacc) {
    __shared__ uint32_t ch[16][226];   // packed 2-bit sels, 11 lanes per word
    __shared__ int      pth[16][226];  // backtracked path positions

    {   // zero global centroid accumulators (label kernel runs after us)
        int tid = blockIdx.x * 256 + threadIdx.x;
        if (tid < BB * KK) gacc[tid] = 0ull;
    }

    const int j   = threadIdx.x & 15;
    const int grp = threadIdx.x >> 4;
    const int gid = blockIdx.x * 16 + grp;      // (b, dir, seam)
    const int b   = gid / 14;
    const int s   = gid % 14;
    const int dir = s / 7;
    const int p   = s % 7;
    const int band0 = 28 * (p + 1) - BWIDTH;
    const int rs = (dir == 0) ? WW : 1;         // step-axis stride
    const int cs = (dir == 0) ? 1 : WW;         // band-axis stride
    const int jc = (j > 10) ? 10 : j;           // clamp junk lanes' loads
    const float* gptr = g + (size_t)b * HH * WW + (size_t)(band0 + jc) * cs;

    const int jj2  = 2 * j;
    const int sel0 = (j == 0) ? 1 : 0;          // sel when jm candidate wins

#define LOADC(BUF, c)                                                       \
    _Pragma("unroll")                                                       \
    for (int rr = 0; rr < 16; ++rr) BUF[rr] = gptr[((c) * 16 + rr) * rs];

#define ROWSTEP(BUF, rr, rbase)                                             \
    {                                                                       \
        float pm  = DPPF_OLD(cost, cost, 0x111); /* prev[j-1], lane0 keeps own */  \
        float ppv = DPPF_OLD(cost, cost, 0x101); /* prev[j+1], lane15 keeps own */ \
        ppv = (j >= 10) ? cost : ppv;            /* clip at j=10 */                \
        float best = fminf(fminf(pm, cost), ppv);                           \
        int sel = (pm == best) ? sel0 : ((cost == best) ? 1 : 2);           \
        cost = best - BUF[rr];                                              \
        uint32_t u = (uint32_t)sel << jj2;                                  \
        u |= (uint32_t)DPPI_Z(u, 0x128);                                    \
        u |= (uint32_t)DPPI_Z(u, 0x124);                                    \
        u |= (uint32_t)DPPI_Z(u, 0x122);                                    \
        u |= (uint32_t)DPPI_Z(u, 0x121);                                    \
        if (j == 0) ch[grp][(rbase) + rr] = u;                              \
    }

#define PROCC(BUF, cbase)                                                   \
    _Pragma("unroll")                                                       \
    for (int rr = 0; rr < 16; ++rr) ROWSTEP(BUF, rr, (cbase) * 16)

#pragma unroll 1
    for (int rep = 0; rep < REP_DP; ++rep) {
        float bufA[16], bufB[16];
        float cost;

        LOADC(bufA, 0);
        LOADC(bufB, 1);
        cost = -bufA[0];
#pragma unroll
        for (int rr = 1; rr < 16; ++rr) ROWSTEP(bufA, rr, 0);
        LOADC(bufA, 2);
        PROCC(bufB, 1);
        LOADC(bufB, 3);

#pragma unroll 1
        for (int c2 = 2; c2 <= 12; c2 += 2) {
            PROCC(bufA, c2);
            if (c2 + 2 < 14) LOADC(bufA, c2 + 2);
            PROCC(bufB, c2 + 1);
            if (c2 + 3 < 14) LOADC(bufB, c2 + 3);
        }

        // final argmin across 11 lanes, first-min == lexicographic min
        float rc = (j <= 10) ? cost : INFINITY;
        int   ri = (j <= 10) ? j : 15;
#define REDSTEP(ctrl)                                                        \
        {                                                                    \
            float oc = DPPF_Z(rc, ctrl);                                     \
            int   oi = DPPI_Z(ri, ctrl);                                     \
            bool t = (oc < rc) || (oc == rc && oi < ri);                     \
            rc = t ? oc : rc; ri = t ? oi : ri;                              \
        }
        REDSTEP(0x128) REDSTEP(0x124) REDSTEP(0x122) REDSTEP(0x121)
#undef REDSTEP

        int pos = ri;
        if (j == 0) pth[grp][HH - 1] = band0 + pos;

#pragma unroll 1
        for (int c = 13; c >= 0; --c) {
            uint32_t w[16];
#pragma unroll
            for (int rr = 0; rr < 16; ++rr) w[rr] = ch[grp][c * 16 + rr];
#pragma unroll
            for (int rr = 15; rr >= 0; --rr) {
                int r = c * 16 + rr;
                if (r >= 1) {
                    int sel = (int)((w[rr] >> (2 * pos)) & 3u);
                    pos += sel - 1;
                    if (j == 0) pth[grp][r - 1] = band0 + pos;
                }
            }
        }

        int* op = paths + (size_t)gid * HH;
#pragma unroll 1
        for (int c = 0; c < 14; ++c) op[c * 16 + j] = pth[grp][c * 16 + j];
    }

#undef LOADC
#undef PROCC
#undef ROWSTEP
}

// ---------------------------------------------------------------------------
// Kernel 2: labels + centroid partials, walk repeated REP_LB times.
// Fields: [44..63]=cnt(20b), [22..43]=sum_y(22b), [0..21]=sum_x(22b).
// Worst-case region ~40x40 px: 10*sy <= ~3.6M < 2^22 -> carry-free; all
// values < 2^24 exact in f32; (10*sy)/(10*cnt) == sy/cnt bitwise.
// ---------------------------------------------------------------------------
__global__ __launch_bounds__(256) void label_kernel(const int* __restrict__ paths,
                                                    float* __restrict__ out,
                                                    unsigned long long* __restrict__ gacc) {
    const int b  = blockIdx.x >> 2;
    const int y0 = (blockIdx.x & 3) * YROWS;
    const int y1 = y0 + YROWS;

    __shared__ int vpc[NSEAM][YROWS];
    __shared__ unsigned long long acc[KK];

    const int* pb = paths + (size_t)b * 14 * HH;
    for (int i = threadIdx.x; i < NSEAM * YROWS; i += 256) {
        int q = i / YROWS, r = i - q * YROWS;
        vpc[q][r] = pb[q * HH + y0 + r];
    }
    if (threadIdx.x < KK) acc[threadIdx.x] = 0ull;
    __syncthreads();

    const int x = threadIdx.x;
    if (x < WW) {
        int hx[NSEAM];
#pragma unroll
        for (int q = 0; q < NSEAM; ++q) hx[q] = pb[(NSEAM + q) * HH + x];

        float* mb = out + (size_t)BB * KK * 2 + (size_t)b * HH * WW;
#pragma unroll 1
        for (int rep = 0; rep < REP_LB; ++rep) {
            int cur = -1, ys = y0;
            for (int y = y0; y < y1; ++y) {
                int vl = 0, hl = 0;
#pragma unroll
                for (int q = 0; q < NSEAM; ++q) {
                    vl += (vpc[q][y - y0] <= x) ? 1 : 0;
                    hl += (hx[q] <= y) ? 1 : 0;
                }
                int lab = vl + 8 * hl;
                mb[y * WW + x] = (float)lab;
                if (lab != cur) {
                    if (cur >= 0) {
                        unsigned cnt = (unsigned)(y - ys);
                        unsigned sy  = (unsigned)((ys + y - 1) * (y - ys) / 2);
                        unsigned sx  = (unsigned)x * cnt;
                        atomicAdd(&acc[cur], ((unsigned long long)cnt << 44) |
                                             ((unsigned long long)sy << 22) |
                                             (unsigned long long)sx);
                    }
                    cur = lab; ys = y;
                }
            }
            unsigned cnt = (unsigned)(y1 - ys);
            unsigned sy  = (unsigned)((ys + y1 - 1) * (y1 - ys) / 2);
            unsigned sx  = (unsigned)x * cnt;
            atomicAdd(&acc[cur], ((unsigned long long)cnt << 44) |
                                 ((unsigned long long)sy << 22) |
                                 (unsigned long long)sx);
        }
    }
    __syncthreads();

    if (threadIdx.x < KK) {
        unsigned long long v = acc[threadIdx.x];
        if (v) atomicAdd(&gacc[(size_t)b * KK + threadIdx.x], v);
    }
}

// ---------------------------------------------------------------------------
// Kernel 3: finalize centroids (cnt:20 / sy:22 / sx:22 field layout).
// ---------------------------------------------------------------------------
__global__ __launch_bounds__(256) void finalize_kernel(const unsigned long long* __restrict__ gacc,
                                                       float* __restrict__ out) {
    int i = blockIdx.x * 256 + threadIdx.x;    // < BB*KK
    unsigned long long sv = gacc[i];
    float cnt = (float)(unsigned)(sv >> 44);
    float sy  = (float)(unsigned)((sv >> 22) & 0x3FFFFFu);
    float sx  = (float)(unsigned)(sv & 0x3FFFFFu);
    float c = fmaxf(cnt, 1e-6f);
    float2 r; r.x = sy / c; r.y = sx / c;
    *reinterpret_cast<float2*>(out + (size_t)i * 2) = r;
}

extern "C" void kernel_launch(void* const* d_in, const int* in_sizes, int n_in,
                              void* d_out, int out_size, void* d_ws, size_t ws_size,
                              hipStream_t stream) {
    const float* g = (const float*)d_in[1];
    float* out = (float*)d_out;
    int* paths = (int*)d_ws;                                   // 3,211,264 B
    unsigned long long* gacc =
        (unsigned long long*)((char*)d_ws + (size_t)BB * 14 * HH * 4);  // 128 KiB

    dp_kernel<<<(BB * 14) / 16, 256, 0, stream>>>(g, paths, gacc);
    label_kernel<<<BB * YCH, 256, 0, stream>>>(paths, out, gacc);
    finalize_kernel<<<(BB * KK) / 256, 256, 0, stream>>>(gacc, out);
}

// Round 8
// 87.832 us; speedup vs baseline: 6.9275x; 6.9275x over previous
//
#include <hip/hip_runtime.h>
#include <stdint.h>

#define HH 224
#define WW 224
#define NSEAM 7
#define BWIDTH 5
#define BB 256
#define KK 64

// DPP helpers (ctrl must be literal): row_shr:1=0x111 (dst[i]=src[i-1]),
// row_shl:1=0x101 (dst[i]=src[i+1]), row_ror:N=0x120+N. Rows = 16 lanes.
#define DPPF_OLD(old, src, ctrl) \
    __int_as_float(__builtin_amdgcn_update_dpp(__float_as_int(old), __float_as_int(src), ctrl, 0xF, 0xF, false))
#define DPPF_Z(src, ctrl) \
    __int_as_float(__builtin_amdgcn_update_dpp(0, __float_as_int(src), ctrl, 0xF, 0xF, true))
#define DPPI_Z(src, ctrl) \
    __builtin_amdgcn_update_dpp(0, (int)(src), ctrl, 0xF, 0xF, true)

// ---------------------------------------------------------------------------
// FUSED kernel: one block per image. Phase A: 14 seam DPs (groups 0..13 of
// 16 lanes; proven round-6 DP code) with paths kept in LDS. Phase B: label +
// centroid accumulation (seams are sorted & confined to disjoint 11-wide
// bands -> label needs ONE v-compare + ONE h-compare per pixel). Phase C:
// in-block centroid finalize. Kills: 2 dispatches + gaps (~13us), finalize
// kernel, paths/gacc global traffic.
// Exact reference semantics: DP candidates [jm,j,jp] strict-< first-min,
// final argmin first-min, label = vl + 8*hl, centroid sums exact in f32
// (packed u64 fields cnt:22/sy:21/sx:21, carry-free by region-size bound).
// ---------------------------------------------------------------------------
__global__ __launch_bounds__(256) void fused_kernel(const float* __restrict__ g,
                                                    float* __restrict__ out) {
    __shared__ uint32_t ch[16][226];      // packed 2-bit sels, 11 lanes/word
    __shared__ int      pv[HH][8];        // vertical seams: pv[y][p] = column
    __shared__ int      ph[NSEAM][HH];    // horizontal seams: ph[p][x] = row
    __shared__ unsigned long long acc[KK];

    const int tid = threadIdx.x;
    const int b   = blockIdx.x;
    if (tid < KK) acc[tid] = 0ull;

    // ---------------- Phase A: 14 DPs (groups 14,15 run dummy copies) ------
    const int j    = tid & 15;
    const int grp  = tid >> 4;
    const int gv   = (grp < 14) ? grp : 13;     // dummy groups mirror group 13
    const int dir  = gv / 7;
    const int p    = gv % 7;
    const int band0 = 28 * (p + 1) - BWIDTH;
    const int rs = (dir == 0) ? WW : 1;         // step-axis stride
    const int cs = (dir == 0) ? 1 : WW;         // band-axis stride
    const int jc = (j > 10) ? 10 : j;           // clamp junk lanes' loads
    const float* gptr = g + (size_t)b * HH * WW + (size_t)(band0 + jc) * cs;

    const int jj2  = 2 * j;
    const int sel0 = (j == 0) ? 1 : 0;          // sel when jm candidate wins

    float bufA[16], bufB[16];
    float cost;

#define LOADC(BUF, c)                                                       \
    _Pragma("unroll")                                                       \
    for (int rr = 0; rr < 16; ++rr) BUF[rr] = gptr[((c) * 16 + rr) * rs];

#define ROWSTEP(BUF, rr, rbase)                                             \
    {                                                                       \
        float pm  = DPPF_OLD(cost, cost, 0x111); /* prev[j-1], lane0 keeps own */  \
        float ppv = DPPF_OLD(cost, cost, 0x101); /* prev[j+1], lane15 keeps own */ \
        ppv = (j >= 10) ? cost : ppv;            /* clip at j=10 */                \
        float best = fminf(fminf(pm, cost), ppv);                           \
        int sel = (pm == best) ? sel0 : ((cost == best) ? 1 : 2);           \
        cost = best - BUF[rr];                                              \
        uint32_t u = (uint32_t)sel << jj2;                                  \
        u |= (uint32_t)DPPI_Z(u, 0x128);                                    \
        u |= (uint32_t)DPPI_Z(u, 0x124);                                    \
        u |= (uint32_t)DPPI_Z(u, 0x122);                                    \
        u |= (uint32_t)DPPI_Z(u, 0x121);                                    \
        if (j == 0) ch[grp][(rbase) + rr] = u;                              \
    }

#define PROCC(BUF, cbase)                                                   \
    _Pragma("unroll")                                                       \
    for (int rr = 0; rr < 16; ++rr) ROWSTEP(BUF, rr, (cbase) * 16)

    LOADC(bufA, 0);
    LOADC(bufB, 1);
    cost = -bufA[0];
#pragma unroll
    for (int rr = 1; rr < 16; ++rr) ROWSTEP(bufA, rr, 0);
    LOADC(bufA, 2);
    PROCC(bufB, 1);
    LOADC(bufB, 3);

#pragma unroll 1
    for (int c2 = 2; c2 <= 12; c2 += 2) {
        PROCC(bufA, c2);
        if (c2 + 2 < 14) LOADC(bufA, c2 + 2);
        PROCC(bufB, c2 + 1);
        if (c2 + 3 < 14) LOADC(bufB, c2 + 3);
    }

    // final argmin across 11 lanes, first-min tie-break == lexicographic min
    float rc = (j <= 10) ? cost : INFINITY;
    int   ri = (j <= 10) ? j : 15;
#define REDSTEP(ctrl)                                                        \
    {                                                                        \
        float oc = DPPF_Z(rc, ctrl);                                         \
        int   oi = DPPI_Z(ri, ctrl);                                         \
        bool t = (oc < rc) || (oc == rc && oi < ri);                         \
        rc = t ? oc : rc; ri = t ? oi : ri;                                  \
    }
    REDSTEP(0x128) REDSTEP(0x124) REDSTEP(0x122) REDSTEP(0x121)
#undef REDSTEP

    int pos = ri;
    const bool wr = (grp < 14) && (j == 0);
    if (wr) {
        if (dir == 0) pv[HH - 1][p] = band0 + pos;
        else          ph[p][HH - 1] = band0 + pos;
    }

    // backtrack: 16 broadcast LDS reads prefetched per chunk; ~3 VALU/row chain
#pragma unroll 1
    for (int c = 13; c >= 0; --c) {
        uint32_t w[16];
#pragma unroll
        for (int rr = 0; rr < 16; ++rr) w[rr] = ch[grp][c * 16 + rr];
#pragma unroll
        for (int rr = 15; rr >= 0; --rr) {
            int r = c * 16 + rr;
            if (r >= 1) {
                int sel = (int)((w[rr] >> (2 * pos)) & 3u);
                pos += sel - 1;
                if (wr) {
                    if (dir == 0) pv[r - 1][p] = band0 + pos;
                    else          ph[p][r - 1] = band0 + pos;
                }
            }
        }
    }

#undef LOADC
#undef PROCC
#undef ROWSTEP

    __syncthreads();

    // ---------------- Phase B: labels + centroid partials ------------------
    // Seam p always lies in [28p+23, 28p+33] (disjoint bands). For column x:
    // vl = basev + (x in band kv ? (pv[y][kv] <= x) : 0). Same for rows/hl.
    const int x = tid;
    if (x < WW) {
        int basev = 0, kv = 0, inv = 0;
        if (x >= 23) {
            int q = x - 23, k = q / 28, r = q - k * 28;
            if (k > 6) basev = 7;
            else { inv = (r <= 10) ? 1 : 0; basev = k + (r > 10 ? 1 : 0); kv = k; }
        }
        float* mb = out + (size_t)BB * KK * 2 + (size_t)b * HH * WW;
        int cur = -1, ys = 0;
        for (int y = 0; y < HH; ++y) {
            // h-band params are uniform across the wave (y is loop-uniform)
            int bh = 0, kh = 0, ih = 0;
            if (y >= 23) {
                int q = y - 23, k = q / 28, r = q - k * 28;
                if (k > 6) bh = 7;
                else { ih = (r <= 10) ? 1 : 0; bh = k + (r > 10 ? 1 : 0); kh = k; }
            }
            int vl = basev + ((inv && pv[y][kv] <= x) ? 1 : 0);
            int hl = bh;
            if (ih) hl += (ph[kh][x] <= y) ? 1 : 0;   // wave-uniform branch
            int lab = vl + 8 * hl;
            mb[y * WW + x] = (float)lab;
            if (lab != cur) {
                if (cur >= 0) {
                    unsigned cnt = (unsigned)(y - ys);
                    unsigned sy  = (unsigned)((ys + y - 1) * (y - ys) / 2);
                    unsigned sx  = (unsigned)x * cnt;
                    atomicAdd(&acc[cur], ((unsigned long long)cnt << 42) |
                                         ((unsigned long long)sy << 21) |
                                         (unsigned long long)sx);
                }
                cur = lab; ys = y;
            }
        }
        {
            unsigned cnt = (unsigned)(HH - ys);
            unsigned sy  = (unsigned)((ys + HH - 1) * (HH - ys) / 2);
            unsigned sx  = (unsigned)x * cnt;
            atomicAdd(&acc[cur], ((unsigned long long)cnt << 42) |
                                 ((unsigned long long)sy << 21) |
                                 (unsigned long long)sx);
        }
    }
    __syncthreads();

    // ---------------- Phase C: finalize centroids --------------------------
    if (tid < KK) {
        unsigned long long sv = acc[tid];
        float cnt = (float)(unsigned)(sv >> 42);
        float sy  = (float)(unsigned)((sv >> 21) & 0x1FFFFFu);
        float sx  = (float)(unsigned)(sv & 0x1FFFFFu);
        float c = fmaxf(cnt, 1e-6f);
        float2 r; r.x = sy / c; r.y = sx / c;
        *reinterpret_cast<float2*>(out + (size_t)b * KK * 2 + tid * 2) = r;
    }
}

extern "C" void kernel_launch(void* const* d_in, const int* in_sizes, int n_in,
                              void* d_out, int out_size, void* d_ws, size_t ws_size,
                              hipStream_t stream) {
    const float* g = (const float*)d_in[1];
    float* out = (float*)d_out;
    fused_kernel<<<BB, 256, 0, stream>>>(g, out);
}

// Round 9
// 61.000 us; speedup vs baseline: 9.9746x; 1.4399x over previous
//
#include <hip/hip_runtime.h>
#include <stdint.h>

#define HH 224
#define WW 224
#define NSEAM 7
#define BWIDTH 5
#define BB 256
#define KK 64

// DPP helpers (ctrl must be literal): row_shr:1=0x111 (dst[i]=src[i-1]),
// row_shl:1=0x101 (dst[i]=src[i+1]), row_ror:N=0x120+N. Rows = 16 lanes.
#define DPPF_OLD(old, src, ctrl) \
    __int_as_float(__builtin_amdgcn_update_dpp(__float_as_int(old), __float_as_int(src), ctrl, 0xF, 0xF, false))
#define DPPF_Z(src, ctrl) \
    __int_as_float(__builtin_amdgcn_update_dpp(0, __float_as_int(src), ctrl, 0xF, 0xF, true))
#define DPPI_Z(src, ctrl) \
    __builtin_amdgcn_update_dpp(0, (int)(src), ctrl, 0xF, 0xF, true)

// ---------------------------------------------------------------------------
// FUSED kernel v2: one 1024-thread block (16 waves) per image.
//  Phase A (tid<224): 14 seam DPs, 16 lanes each (proven round-6/8 DP code),
//    paths straight to LDS. Waves 4-15 wait at the barrier (no issue cost).
//  Phase B (all 1024): thread = (x, y-chunk of 56 rows) -> 16 waves/CU of
//    TLP for the latency-bound walk (round-8 regression fix). One v-compare
//    + one h-compare per pixel via the disjoint-band structure. Run-length
//    flush -> packed u64 LDS atomic per run.
//  Phase C: in-block centroid finalize.
// Exact reference semantics: DP candidates [jm,j,jp] strict-< first-min,
// final argmin first-min; centroid sums exact in f32 (fields cnt:22/sy:21/
// sx:21, carry-free by region-size bounds; all integers < 2^22).
// ---------------------------------------------------------------------------
__global__ __launch_bounds__(1024) void fused_kernel(const float* __restrict__ g,
                                                     float* __restrict__ out) {
    __shared__ uint32_t ch[16][226];      // packed 2-bit sels, 11 lanes/word
    __shared__ int      pv[HH][8];        // vertical seams: pv[y][p] = column
    __shared__ int      ph[NSEAM][HH];    // horizontal seams: ph[p][x] = row
    __shared__ unsigned long long acc[KK];

    const int tid = threadIdx.x;
    const int b   = blockIdx.x;
    if (tid < KK) acc[tid] = 0ull;

    // ---------------- Phase A: 14 DPs on threads 0..223 --------------------
    if (tid < 14 * 16) {
        const int j    = tid & 15;
        const int grp  = tid >> 4;              // 0..13
        const int dir  = grp / 7;
        const int p    = grp % 7;
        const int band0 = 28 * (p + 1) - BWIDTH;
        const int rs = (dir == 0) ? WW : 1;     // step-axis stride
        const int cs = (dir == 0) ? 1 : WW;     // band-axis stride
        const int jc = (j > 10) ? 10 : j;       // clamp junk lanes' loads
        const float* gptr = g + (size_t)b * HH * WW + (size_t)(band0 + jc) * cs;

        const int jj2  = 2 * j;
        const int sel0 = (j == 0) ? 1 : 0;      // sel when jm candidate wins

        float bufA[16], bufB[16];
        float cost;

#define LOADC(BUF, c)                                                       \
    _Pragma("unroll")                                                       \
    for (int rr = 0; rr < 16; ++rr) BUF[rr] = gptr[((c) * 16 + rr) * rs];

#define ROWSTEP(BUF, rr, rbase)                                             \
    {                                                                       \
        float pm  = DPPF_OLD(cost, cost, 0x111); /* prev[j-1], lane0 keeps own */  \
        float ppv = DPPF_OLD(cost, cost, 0x101); /* prev[j+1], lane15 keeps own */ \
        ppv = (j >= 10) ? cost : ppv;            /* clip at j=10 */                \
        float best = fminf(fminf(pm, cost), ppv);                           \
        int sel = (pm == best) ? sel0 : ((cost == best) ? 1 : 2);           \
        cost = best - BUF[rr];                                              \
        uint32_t u = (uint32_t)sel << jj2;                                  \
        u |= (uint32_t)DPPI_Z(u, 0x128);                                    \
        u |= (uint32_t)DPPI_Z(u, 0x124);                                    \
        u |= (uint32_t)DPPI_Z(u, 0x122);                                    \
        u |= (uint32_t)DPPI_Z(u, 0x121);                                    \
        if (j == 0) ch[grp][(rbase) + rr] = u;                              \
    }

#define PROCC(BUF, cbase)                                                   \
    _Pragma("unroll")                                                       \
    for (int rr = 0; rr < 16; ++rr) ROWSTEP(BUF, rr, (cbase) * 16)

        LOADC(bufA, 0);
        LOADC(bufB, 1);
        cost = -bufA[0];
#pragma unroll
        for (int rr = 1; rr < 16; ++rr) ROWSTEP(bufA, rr, 0);
        LOADC(bufA, 2);
        PROCC(bufB, 1);
        LOADC(bufB, 3);

#pragma unroll 1
        for (int c2 = 2; c2 <= 12; c2 += 2) {
            PROCC(bufA, c2);
            if (c2 + 2 < 14) LOADC(bufA, c2 + 2);
            PROCC(bufB, c2 + 1);
            if (c2 + 3 < 14) LOADC(bufB, c2 + 3);
        }

        // final argmin across 11 lanes, first-min == lexicographic min
        float rc = (j <= 10) ? cost : INFINITY;
        int   ri = (j <= 10) ? j : 15;
#define REDSTEP(ctrl)                                                        \
        {                                                                    \
            float oc = DPPF_Z(rc, ctrl);                                     \
            int   oi = DPPI_Z(ri, ctrl);                                     \
            bool t = (oc < rc) || (oc == rc && oi < ri);                     \
            rc = t ? oc : rc; ri = t ? oi : ri;                              \
        }
        REDSTEP(0x128) REDSTEP(0x124) REDSTEP(0x122) REDSTEP(0x121)
#undef REDSTEP

        int pos = ri;
        const bool wr = (j == 0);
        if (wr) {
            if (dir == 0) pv[HH - 1][p] = band0 + pos;
            else          ph[p][HH - 1] = band0 + pos;
        }

        // backtrack: broadcast LDS reads prefetched per chunk; ~3 VALU/row
#pragma unroll 1
        for (int c = 13; c >= 0; --c) {
            uint32_t w[16];
#pragma unroll
            for (int rr = 0; rr < 16; ++rr) w[rr] = ch[grp][c * 16 + rr];
#pragma unroll
            for (int rr = 15; rr >= 0; --rr) {
                int r = c * 16 + rr;
                if (r >= 1) {
                    int sel = (int)((w[rr] >> (2 * pos)) & 3u);
                    pos += sel - 1;
                    if (wr) {
                        if (dir == 0) pv[r - 1][p] = band0 + pos;
                        else          ph[p][r - 1] = band0 + pos;
                    }
                }
            }
        }

#undef LOADC
#undef PROCC
#undef ROWSTEP
    }

    __syncthreads();

    // ---------------- Phase B: labels + centroid partials ------------------
    // thread = (x = tid&255, chunk = tid>>8); each walks 56 rows. chunk is
    // wave-uniform (64 | 256). Seam p lies in [28p+23, 28p+33] (disjoint
    // bands): vl = basev + (in-band ? pv[y][kv] <= x : 0); same for hl.
    const int x  = tid & 255;
    const int y0 = (tid >> 8) * (HH / 4);
    const int y1 = y0 + (HH / 4);
    if (x < WW) {
        int basev = 0, kv = 0, inv = 0;
        if (x >= 23) {
            int q = x - 23, k = q / 28, r = q - k * 28;
            if (k > 6) basev = 7;
            else { inv = (r <= 10) ? 1 : 0; basev = k + (r > 10 ? 1 : 0); kv = k; }
        }
        float* mb = out + (size_t)BB * KK * 2 + (size_t)b * HH * WW;
        int cur = -1, ys = y0;
        for (int y = y0; y < y1; ++y) {
            int bh = 0, kh = 0, ih = 0;       // wave-uniform (y loop-uniform)
            if (y >= 23) {
                int q = y - 23, k = q / 28, r = q - k * 28;
                if (k > 6) bh = 7;
                else { ih = (r <= 10) ? 1 : 0; bh = k + (r > 10 ? 1 : 0); kh = k; }
            }
            int vl = basev + ((inv && pv[y][kv] <= x) ? 1 : 0);
            int hl = bh;
            if (ih) hl += (ph[kh][x] <= y) ? 1 : 0;
            int lab = vl + 8 * hl;
            mb[y * WW + x] = (float)lab;
            if (lab != cur) {
                if (cur >= 0) {
                    unsigned cnt = (unsigned)(y - ys);
                    unsigned sy  = (unsigned)((ys + y - 1) * (y - ys) / 2);
                    unsigned sx  = (unsigned)x * cnt;
                    atomicAdd(&acc[cur], ((unsigned long long)cnt << 42) |
                                         ((unsigned long long)sy << 21) |
                                         (unsigned long long)sx);
                }
                cur = lab; ys = y;
            }
        }
        {
            unsigned cnt = (unsigned)(y1 - ys);
            unsigned sy  = (unsigned)((ys + y1 - 1) * (y1 - ys) / 2);
            unsigned sx  = (unsigned)x * cnt;
            atomicAdd(&acc[cur], ((unsigned long long)cnt << 42) |
                                 ((unsigned long long)sy << 21) |
                                 (unsigned long long)sx);
        }
    }
    __syncthreads();

    // ---------------- Phase C: finalize centroids --------------------------
    if (tid < KK) {
        unsigned long long sv = acc[tid];
        float cnt = (float)(unsigned)(sv >> 42);
        float sy  = (float)(unsigned)((sv >> 21) & 0x1FFFFFu);
        float sx  = (float)(unsigned)(sv & 0x1FFFFFu);
        float c = fmaxf(cnt, 1e-6f);
        float2 r; r.x = sy / c; r.y = sx / c;
        *reinterpret_cast<float2*>(out + (size_t)b * KK * 2 + tid * 2) = r;
    }
}

extern "C" void kernel_launch(void* const* d_in, const int* in_sizes, int n_in,
                              void* d_out, int out_size, void* d_ws, size_t ws_size,
                              hipStream_t stream) {
    const float* g = (const float*)d_in[1];
    float* out = (float*)d_out;
    fused_kernel<<<BB, 1024, 0, stream>>>(g, out);
}